// Round 11
// baseline (77.723 us; speedup 1.0000x reference)
//
#include <hip/hip_runtime.h>

#define B_   4
#define C_   64
#define H_   128
#define W_   128
#define KS   7
#define G_   4
#define GC_  16
#define KK   49
#define PAD  3
#define TH   8
#define TW   16
#define HW_  (H_ * W_)
#define ZROWB 288              // LDS z row stride (bytes): 128 px * 2B + 32B pad
#define ZTROW 64               // d_ws z row: 64 dwords = 128 px bf16 (no pad)
#define NTILE 2048             // 16 bz * 16 by * 8 bx

typedef float f32x4  __attribute__((ext_vector_type(4)));
typedef short bf16x8 __attribute__((ext_vector_type(8)));
typedef unsigned int u32x4 __attribute__((ext_vector_type(4)));
typedef unsigned int u32x2 __attribute__((ext_vector_type(2)));

__device__ __forceinline__ unsigned f2bf(float f) {   // RNE float->bf16 (low 16)
    unsigned u = __float_as_uint(f);
    unsigned r = u + 0x7FFFu + ((u >> 16) & 1u);
    return r >> 16;
}

#define BFLO(u) __uint_as_float((u) << 16)
#define BFHI(u) __uint_as_float((u) & 0xFFFF0000u)

// ============ Kernel A: 1x1 conv + BN + SiLU -> z tiles in d_ws ============
__global__ __launch_bounds__(256, 4) void conv_z(
    const float* __restrict__ x,
    const float* __restrict__ cw,
    const float* __restrict__ bng,
    const float* __restrict__ bnb,
    const float* __restrict__ bnm,
    const float* __restrict__ bnv,
    unsigned int* __restrict__ zt_out)
{
    __shared__ __align__(16) unsigned short z_sh[KK * (ZROWB / 2)]; // 14112 B
    __shared__ float sscale[KK], sbias[KK];

    const int tid  = threadIdx.x;
    const int lane = tid & 63;
    const int wv   = tid >> 6;
    const int l15  = lane & 15;
    const int l4   = lane >> 4;

    const int bx = blockIdx.x;
    const int by = blockIdx.y;
    const int bz = blockIdx.z;        // b*G + g
    const int w0 = bx * TW;
    const int h0 = by * TH;
    const int b  = bz >> 2;
    const int g  = bz & 3;

    if (tid < KK) {
        const int o = g * KK + tid;
        const float s = bng[o] * rsqrtf(bnv[o] + 1e-5f);
        sscale[tid] = s;
        sbias[tid]  = bnb[o] - bnm[o] * s;
    }

    // A fragments: A[px][c], px = (wv*2+mt)*16 + l15
    bf16x8 afr[2][2];
    {
        const float* xb = x + (size_t)b * C_ * HW_;
#pragma unroll
        for (int mt = 0; mt < 2; ++mt) {
            const int hh = h0 + wv * 2 + mt;
            const float* xp = xb + hh * W_ + (w0 + l15);
#pragma unroll
            for (int ks = 0; ks < 2; ++ks) {
                const int c0 = ks * 32 + l4 * 8;
                bf16x8 a;
#pragma unroll
                for (int j = 0; j < 8; ++j)
                    a[j] = (short)f2bf(xp[(size_t)(c0 + j) * HW_]);
                afr[mt][ks] = a;
            }
        }
    }

    // B fragments: B[c][k], k = nt*16 + l15 (zero past 49)
    bf16x8 bfr[4][2];
    {
#pragma unroll
        for (int nt = 0; nt < 4; ++nt) {
            const int kout = nt * 16 + l15;
            const bool kv = (kout < KK);
            const float* wp = cw + (size_t)(g * KK + (kv ? kout : 0)) * C_;
#pragma unroll
            for (int ks = 0; ks < 2; ++ks) {
                const int c0 = ks * 32 + l4 * 8;
                bf16x8 bb;
#pragma unroll
                for (int j = 0; j < 8; ++j)
                    bb[j] = kv ? (short)f2bf(wp[c0 + j]) : (short)0;
                bfr[nt][ks] = bb;
            }
        }
    }

    __syncthreads();

    f32x4 acc1[2][4];
#pragma unroll
    for (int mt = 0; mt < 2; ++mt)
#pragma unroll
        for (int nt = 0; nt < 4; ++nt) {
            f32x4 a = {0.f, 0.f, 0.f, 0.f};
            a = __builtin_amdgcn_mfma_f32_16x16x32_bf16(afr[mt][0], bfr[nt][0], a, 0, 0, 0);
            a = __builtin_amdgcn_mfma_f32_16x16x32_bf16(afr[mt][1], bfr[nt][1], a, 0, 0, 0);
            acc1[mt][nt] = a;
        }

    // BN + SiLU -> bf16 -> z_sh[k][px]
#pragma unroll
    for (int nt = 0; nt < 4; ++nt) {
        const int k = nt * 16 + l15;
        if (k < KK) {
            const float sc = sscale[k];
            const float bi = sbias[k];
#pragma unroll
            for (int mt = 0; mt < 2; ++mt) {
                const int px0 = (wv * 2 + mt) * 16 + l4 * 4;
                const float t0 = acc1[mt][nt][0] * sc + bi;
                const float t1 = acc1[mt][nt][1] * sc + bi;
                const float t2 = acc1[mt][nt][2] * sc + bi;
                const float t3 = acc1[mt][nt][3] * sc + bi;
                const float v0 = __fdividef(t0, 1.0f + __expf(-t0));
                const float v1 = __fdividef(t1, 1.0f + __expf(-t1));
                const float v2 = __fdividef(t2, 1.0f + __expf(-t2));
                const float v3 = __fdividef(t3, 1.0f + __expf(-t3));
                u32x2 wpk;
                wpk[0] = f2bf(v0) | (f2bf(v1) << 16);
                wpk[1] = f2bf(v2) | (f2bf(v3) << 16);
                *(u32x2*)((char*)z_sh + k * ZROWB + px0 * 2) = wpk;
            }
        }
    }

    __syncthreads();

    // coalesced dump: z_sh payload (49 x 256B) -> d_ws tile
    const int tileIdx = (bz * (H_ / TH) + by) * (W_ / TW) + bx;
    unsigned int* dst = zt_out + (size_t)tileIdx * (KK * ZTROW);
    for (int i = tid; i < KK * 32; i += 256) {          // 8B units
        const int k = i >> 5, j = i & 31;
        const u32x2 v = *(const u32x2*)((const char*)z_sh + k * ZROWB + j * 8);
        *(u32x2*)(dst + i * 2) = v;
    }
}

// ============ Kernel B: involution (no LDS, no barriers) ============
__global__ __launch_bounds__(256, 4) void invol_apply(
    const float* __restrict__ x,
    const unsigned int* __restrict__ zt_in,
    float* __restrict__ out)
{
    const int tid = threadIdx.x;
    const int bx = blockIdx.x;
    const int by = blockIdx.y;
    const int bz = blockIdx.z;        // b*G + g
    const int w0 = bx * TW;
    const int h0 = by * TH;
    const int b  = bz >> 2;
    const int g  = bz & 3;

    const int c2 = tid >> 4;          // 0..15
    const int y8 = (tid >> 1) & 7;    // 0..7
    const int xh = tid & 1;           // 0..1
    const bool ledge = (bx == 0) & (xh == 0);
    const bool redge = (bx == W_ / TW - 1) & (xh == 1);

    const int tileIdx = (bz * (H_ / TH) + by) * (W_ / TW) + bx;
    const char* zby = (const char*)(zt_in + (size_t)tileIdx * (KK * ZTROW))
                      + y8 * 32 + xh * 16;   // + k*256

    float a0 = 0.f, a1 = 0.f, a2 = 0.f, a3 = 0.f;
    float a4 = 0.f, a5 = 0.f, a6 = 0.f, a7 = 0.f;

    const float* xc = x + (size_t)(b * C_ + g * GC_ + c2) * HW_;

#pragma unroll 1
    for (int kh = 0; kh < KS; ++kh) {
        const int gh = h0 + y8 + kh - PAD;
        const bool rowok = (gh >= 0) & (gh < H_);
        const int ghc = gh < 0 ? 0 : (gh > H_ - 1 ? H_ - 1 : gh);
        const float* rp = xc + (size_t)ghc * W_;

        float f0, f1, f2, f3, f4, f5, f6, f7, f8, f9, f10, f11, f12, f13;
        if (ledge) {
            const f32x4* vp = (const f32x4*)rp;               // x = 0..11
            const f32x4 q0 = vp[0], q1 = vp[1], q2 = vp[2];
            f0 = 0.f; f1 = 0.f; f2 = 0.f;
            f3 = q0[0]; f4 = q0[1]; f5 = q0[2]; f6 = q0[3];
            f7 = q1[0]; f8 = q1[1]; f9 = q1[2]; f10 = q1[3];
            f11 = q2[0]; f12 = q2[1]; f13 = q2[2];
        } else if (redge) {
            const f32x4* vp = (const f32x4*)(rp + 116);       // x = 116..127
            const f32x4 q0 = vp[0], q1 = vp[1], q2 = vp[2];
            f0 = q0[1]; f1 = q0[2]; f2 = q0[3];
            f3 = q1[0]; f4 = q1[1]; f5 = q1[2]; f6 = q1[3];
            f7 = q2[0]; f8 = q2[1]; f9 = q2[2]; f10 = q2[3];
            f11 = 0.f; f12 = 0.f; f13 = 0.f;
        } else {
            const f32x4* vp = (const f32x4*)(rp + w0 + xh * 8 - 4);
            const f32x4 q0 = vp[0], q1 = vp[1], q2 = vp[2], q3 = vp[3];
            f0 = q0[1]; f1 = q0[2]; f2 = q0[3];
            f3 = q1[0]; f4 = q1[1]; f5 = q1[2]; f6 = q1[3];
            f7 = q2[0]; f8 = q2[1]; f9 = q2[2]; f10 = q2[3];
            f11 = q3[0]; f12 = q3[1]; f13 = q3[2];
        }
        float row[14] = { f0, f1, f2, f3, f4, f5, f6, f7, f8, f9, f10, f11, f12, f13 };

        if (rowok) {
#pragma unroll
            for (int kw = 0; kw < KS; ++kw) {
                const int k = kh * KS + kw;
                const u32x4 q = *(const u32x4*)(zby + k * 256);   // 8 px
                a0 = fmaf(BFLO(q[0]), row[kw + 0], a0);
                a1 = fmaf(BFHI(q[0]), row[kw + 1], a1);
                a2 = fmaf(BFLO(q[1]), row[kw + 2], a2);
                a3 = fmaf(BFHI(q[1]), row[kw + 3], a3);
                a4 = fmaf(BFLO(q[2]), row[kw + 4], a4);
                a5 = fmaf(BFHI(q[2]), row[kw + 5], a5);
                a6 = fmaf(BFLO(q[3]), row[kw + 6], a6);
                a7 = fmaf(BFHI(q[3]), row[kw + 7], a7);
            }
        }
    }

    float* og = out + (size_t)(b * C_ + g * GC_ + c2) * HW_
                    + (h0 + y8) * W_ + w0 + xh * 8;
    {
        f32x4 v;
        v[0] = a0; v[1] = a1; v[2] = a2; v[3] = a3;
        *(f32x4*)(og + 0) = v;
        v[0] = a4; v[1] = a5; v[2] = a6; v[3] = a7;
        *(f32x4*)(og + 4) = v;
    }
}

// ============ Fallback: round-10 fused kernel (used if ws too small) ============
__global__ __launch_bounds__(256, 4) void invol_fused_fb(
    const float* __restrict__ x,
    const float* __restrict__ cw,
    const float* __restrict__ bng,
    const float* __restrict__ bnb,
    const float* __restrict__ bnm,
    const float* __restrict__ bnv,
    float* __restrict__ out)
{
    __shared__ __align__(16) unsigned short z_sh[KK * (ZROWB / 2)];
    __shared__ float sscale[KK], sbias[KK];

    const int tid  = threadIdx.x;
    const int lane = tid & 63;
    const int wv   = tid >> 6;
    const int l15  = lane & 15;
    const int l4   = lane >> 4;

    const int bx = blockIdx.x;
    const int w0 = bx * TW;
    const int h0 = blockIdx.y * TH;
    const int bz = blockIdx.z;
    const int b  = bz >> 2;
    const int g  = bz & 3;

    if (tid < KK) {
        const int o = g * KK + tid;
        const float s = bng[o] * rsqrtf(bnv[o] + 1e-5f);
        sscale[tid] = s;
        sbias[tid]  = bnb[o] - bnm[o] * s;
    }

    bf16x8 afr[2][2];
    {
        const float* xb = x + (size_t)b * C_ * HW_;
#pragma unroll
        for (int mt = 0; mt < 2; ++mt) {
            const int hh = h0 + wv * 2 + mt;
            const float* xp = xb + hh * W_ + (w0 + l15);
#pragma unroll
            for (int ks = 0; ks < 2; ++ks) {
                const int c0 = ks * 32 + l4 * 8;
                bf16x8 a;
#pragma unroll
                for (int j = 0; j < 8; ++j)
                    a[j] = (short)f2bf(xp[(size_t)(c0 + j) * HW_]);
                afr[mt][ks] = a;
            }
        }
    }

    bf16x8 bfr[4][2];
    {
#pragma unroll
        for (int nt = 0; nt < 4; ++nt) {
            const int kout = nt * 16 + l15;
            const bool kv = (kout < KK);
            const float* wp = cw + (size_t)(g * KK + (kv ? kout : 0)) * C_;
#pragma unroll
            for (int ks = 0; ks < 2; ++ks) {
                const int c0 = ks * 32 + l4 * 8;
                bf16x8 bb;
#pragma unroll
                for (int j = 0; j < 8; ++j)
                    bb[j] = kv ? (short)f2bf(wp[c0 + j]) : (short)0;
                bfr[nt][ks] = bb;
            }
        }
    }

    __syncthreads();

    f32x4 acc1[2][4];
#pragma unroll
    for (int mt = 0; mt < 2; ++mt)
#pragma unroll
        for (int nt = 0; nt < 4; ++nt) {
            f32x4 a = {0.f, 0.f, 0.f, 0.f};
            a = __builtin_amdgcn_mfma_f32_16x16x32_bf16(afr[mt][0], bfr[nt][0], a, 0, 0, 0);
            a = __builtin_amdgcn_mfma_f32_16x16x32_bf16(afr[mt][1], bfr[nt][1], a, 0, 0, 0);
            acc1[mt][nt] = a;
        }

#pragma unroll
    for (int nt = 0; nt < 4; ++nt) {
        const int k = nt * 16 + l15;
        if (k < KK) {
            const float sc = sscale[k];
            const float bi = sbias[k];
#pragma unroll
            for (int mt = 0; mt < 2; ++mt) {
                const int px0 = (wv * 2 + mt) * 16 + l4 * 4;
                const float t0 = acc1[mt][nt][0] * sc + bi;
                const float t1 = acc1[mt][nt][1] * sc + bi;
                const float t2 = acc1[mt][nt][2] * sc + bi;
                const float t3 = acc1[mt][nt][3] * sc + bi;
                const float v0 = __fdividef(t0, 1.0f + __expf(-t0));
                const float v1 = __fdividef(t1, 1.0f + __expf(-t1));
                const float v2 = __fdividef(t2, 1.0f + __expf(-t2));
                const float v3 = __fdividef(t3, 1.0f + __expf(-t3));
                u32x2 wpk;
                wpk[0] = f2bf(v0) | (f2bf(v1) << 16);
                wpk[1] = f2bf(v2) | (f2bf(v3) << 16);
                *(u32x2*)((char*)z_sh + k * ZROWB + px0 * 2) = wpk;
            }
        }
    }

    __syncthreads();

    const int c2 = tid >> 4;
    const int y8 = (tid >> 1) & 7;
    const int xh = tid & 1;
    const bool ledge = (bx == 0) & (xh == 0);
    const bool redge = (bx == W_ / TW - 1) & (xh == 1);

    float a0 = 0.f, a1 = 0.f, a2 = 0.f, a3 = 0.f;
    float a4 = 0.f, a5 = 0.f, a6 = 0.f, a7 = 0.f;

    const float* xc = x + (size_t)(b * C_ + g * GC_ + c2) * HW_;
    const char* zby = (const char*)z_sh + y8 * 32 + xh * 16;

#pragma unroll 1
    for (int kh = 0; kh < KS; ++kh) {
        const int gh = h0 + y8 + kh - PAD;
        const bool rowok = (gh >= 0) & (gh < H_);
        const int ghc = gh < 0 ? 0 : (gh > H_ - 1 ? H_ - 1 : gh);
        const float* rp = xc + (size_t)ghc * W_;

        float f0, f1, f2, f3, f4, f5, f6, f7, f8, f9, f10, f11, f12, f13;
        if (ledge) {
            const f32x4* vp = (const f32x4*)rp;
            const f32x4 q0 = vp[0], q1 = vp[1], q2 = vp[2];
            f0 = 0.f; f1 = 0.f; f2 = 0.f;
            f3 = q0[0]; f4 = q0[1]; f5 = q0[2]; f6 = q0[3];
            f7 = q1[0]; f8 = q1[1]; f9 = q1[2]; f10 = q1[3];
            f11 = q2[0]; f12 = q2[1]; f13 = q2[2];
        } else if (redge) {
            const f32x4* vp = (const f32x4*)(rp + 116);
            const f32x4 q0 = vp[0], q1 = vp[1], q2 = vp[2];
            f0 = q0[1]; f1 = q0[2]; f2 = q0[3];
            f3 = q1[0]; f4 = q1[1]; f5 = q1[2]; f6 = q1[3];
            f7 = q2[0]; f8 = q2[1]; f9 = q2[2]; f10 = q2[3];
            f11 = 0.f; f12 = 0.f; f13 = 0.f;
        } else {
            const f32x4* vp = (const f32x4*)(rp + w0 + xh * 8 - 4);
            const f32x4 q0 = vp[0], q1 = vp[1], q2 = vp[2], q3 = vp[3];
            f0 = q0[1]; f1 = q0[2]; f2 = q0[3];
            f3 = q1[0]; f4 = q1[1]; f5 = q1[2]; f6 = q1[3];
            f7 = q2[0]; f8 = q2[1]; f9 = q2[2]; f10 = q2[3];
            f11 = q3[0]; f12 = q3[1]; f13 = q3[2];
        }
        float row[14] = { f0, f1, f2, f3, f4, f5, f6, f7, f8, f9, f10, f11, f12, f13 };

        if (rowok) {
            const char* zrow = zby + kh * (KS * ZROWB);
#pragma unroll
            for (int kw = 0; kw < KS; ++kw) {
                const u32x4 q = *(const u32x4*)(zrow + kw * ZROWB);
                a0 = fmaf(BFLO(q[0]), row[kw + 0], a0);
                a1 = fmaf(BFHI(q[0]), row[kw + 1], a1);
                a2 = fmaf(BFLO(q[1]), row[kw + 2], a2);
                a3 = fmaf(BFHI(q[1]), row[kw + 3], a3);
                a4 = fmaf(BFLO(q[2]), row[kw + 4], a4);
                a5 = fmaf(BFHI(q[2]), row[kw + 5], a5);
                a6 = fmaf(BFLO(q[3]), row[kw + 6], a6);
                a7 = fmaf(BFHI(q[3]), row[kw + 7], a7);
            }
        }
    }

    float* og = out + (size_t)(b * C_ + g * GC_ + c2) * HW_
                    + (h0 + y8) * W_ + w0 + xh * 8;
    {
        f32x4 v;
        v[0] = a0; v[1] = a1; v[2] = a2; v[3] = a3;
        *(f32x4*)(og + 0) = v;
        v[0] = a4; v[1] = a5; v[2] = a6; v[3] = a7;
        *(f32x4*)(og + 4) = v;
    }
}

extern "C" void kernel_launch(void* const* d_in, const int* in_sizes, int n_in,
                              void* d_out, int out_size, void* d_ws, size_t ws_size,
                              hipStream_t stream) {
    const float* x   = (const float*)d_in[0];
    const float* cw  = (const float*)d_in[1];
    const float* bng = (const float*)d_in[2];
    const float* bnb = (const float*)d_in[3];
    const float* bnm = (const float*)d_in[4];
    const float* bnv = (const float*)d_in[5];
    float* out = (float*)d_out;

    dim3 grid(W_ / TW, H_ / TH, B_ * G_);   // 8 x 16 x 16 = 2048 blocks
    dim3 block(256);

    const size_t needed = (size_t)NTILE * KK * ZTROW * 4;   // 25,690,112 B
    if (ws_size >= needed) {
        unsigned int* zt = (unsigned int*)d_ws;
        conv_z<<<grid, block, 0, stream>>>(x, cw, bng, bnb, bnm, bnv, zt);
        invol_apply<<<grid, block, 0, stream>>>(x, zt, out);
    } else {
        invol_fused_fb<<<grid, block, 0, stream>>>(x, cw, bng, bnb, bnm, bnv, out);
    }
}

// Round 13
// 51.214 us; speedup vs baseline: 1.5176x; 1.5176x over previous
//
#include <hip/hip_runtime.h>

#define B_   4
#define C_   64
#define H_   128
#define W_   128
#define KS   7
#define G_   4
#define GC_  16
#define KK   49
#define PAD  3
#define TH   8
#define TW   16
#define HW_  (H_ * W_)
#define ZROWB 288              // LDS z row stride (bytes): 128 px * 2B + 32B pad

typedef float f32x4  __attribute__((ext_vector_type(4)));
typedef short bf16x8 __attribute__((ext_vector_type(8)));
typedef unsigned int u32x4 __attribute__((ext_vector_type(4)));
typedef unsigned int u32x2 __attribute__((ext_vector_type(2)));

__device__ __forceinline__ unsigned f2bf(float f) {   // RNE float->bf16 (low 16)
    unsigned u = __float_as_uint(f);
    unsigned r = u + 0x7FFFu + ((u >> 16) & 1u);
    return r >> 16;
}

#define BFLO(u) __uint_as_float((u) << 16)
#define BFHI(u) __uint_as_float((u) & 0xFFFF0000u)

__global__ __launch_bounds__(256, 4) void invol_mfma9(
    const float* __restrict__ x,
    const float* __restrict__ cw,
    const float* __restrict__ bng,
    const float* __restrict__ bnb,
    const float* __restrict__ bnm,
    const float* __restrict__ bnv,
    float* __restrict__ out)
{
    __shared__ __align__(16) unsigned short z_sh[KK * (ZROWB / 2)]; // 14112 B
    __shared__ float sscale[KK], sbias[KK];

    const int tid  = threadIdx.x;
    const int lane = tid & 63;
    const int wv   = tid >> 6;
    const int l15  = lane & 15;
    const int l4   = lane >> 4;

    // ---- XCD-locality swizzle: consecutive flat ids round-robin XCDs, so
    // bid&7 selects the XCD. Map each XCD to ONE (image b, g-pair): its x
    // footprint (4 MB) == one XCD's L2. Bijective over 2048 blocks.
    const int bid = blockIdx.x;
    const int xcd = bid & 7;
    const int s   = bid >> 3;          // 0..255 within XCD
    const int b   = xcd >> 1;
    const int g   = (xcd & 1) * 2 + (s >> 7);
    const int by  = (s >> 3) & 15;
    const int bx  = s & 7;
    const int w0  = bx * TW;
    const int h0  = by * TH;

    // ---- BN constants ----
    if (tid < KK) {
        const int o = g * KK + tid;
        const float sc = bng[o] * rsqrtf(bnv[o] + 1e-5f);
        sscale[tid] = sc;
        sbias[tid]  = bnb[o] - bnm[o] * sc;
    }

    // ---- A fragments: A[px][c], px = (wv*2+mt)*16 + l15 ----
    bf16x8 afr[2][2];
    {
        const float* xb = x + (size_t)b * C_ * HW_;
#pragma unroll
        for (int mt = 0; mt < 2; ++mt) {
            const int hh = h0 + wv * 2 + mt;
            const float* xp = xb + hh * W_ + (w0 + l15);
#pragma unroll
            for (int ks = 0; ks < 2; ++ks) {
                const int c0 = ks * 32 + l4 * 8;
                bf16x8 a;
#pragma unroll
                for (int j = 0; j < 8; ++j)
                    a[j] = (short)f2bf(xp[(size_t)(c0 + j) * HW_]);
                afr[mt][ks] = a;
            }
        }
    }

    // ---- B fragments: B[c][k], k = nt*16 + l15 (zero past 49) ----
    bf16x8 bfr[4][2];
    {
#pragma unroll
        for (int nt = 0; nt < 4; ++nt) {
            const int kout = nt * 16 + l15;
            const bool kv = (kout < KK);
            const float* wp = cw + (size_t)(g * KK + (kv ? kout : 0)) * C_;
#pragma unroll
            for (int ks = 0; ks < 2; ++ks) {
                const int c0 = ks * 32 + l4 * 8;
                bf16x8 bb;
#pragma unroll
                for (int j = 0; j < 8; ++j)
                    bb[j] = kv ? (short)f2bf(wp[c0 + j]) : (short)0;
                bfr[nt][ks] = bb;
            }
        }
    }

    __syncthreads();

    // ---- MFMA: z[px][k] ----
    f32x4 acc1[2][4];
#pragma unroll
    for (int mt = 0; mt < 2; ++mt)
#pragma unroll
        for (int nt = 0; nt < 4; ++nt) {
            f32x4 a = {0.f, 0.f, 0.f, 0.f};
            a = __builtin_amdgcn_mfma_f32_16x16x32_bf16(afr[mt][0], bfr[nt][0], a, 0, 0, 0);
            a = __builtin_amdgcn_mfma_f32_16x16x32_bf16(afr[mt][1], bfr[nt][1], a, 0, 0, 0);
            acc1[mt][nt] = a;
        }

    // ---- epilogue: BN+SiLU -> bf16 -> z_sh[k][px] ----
#pragma unroll
    for (int nt = 0; nt < 4; ++nt) {
        const int k = nt * 16 + l15;
        if (k < KK) {
            const float sc = sscale[k];
            const float bi = sbias[k];
#pragma unroll
            for (int mt = 0; mt < 2; ++mt) {
                const int px0 = (wv * 2 + mt) * 16 + l4 * 4;
                const float t0 = acc1[mt][nt][0] * sc + bi;
                const float t1 = acc1[mt][nt][1] * sc + bi;
                const float t2 = acc1[mt][nt][2] * sc + bi;
                const float t3 = acc1[mt][nt][3] * sc + bi;
                const float v0 = __fdividef(t0, 1.0f + __expf(-t0));
                const float v1 = __fdividef(t1, 1.0f + __expf(-t1));
                const float v2 = __fdividef(t2, 1.0f + __expf(-t2));
                const float v3 = __fdividef(t3, 1.0f + __expf(-t3));
                u32x2 wpk;
                wpk[0] = f2bf(v0) | (f2bf(v1) << 16);
                wpk[1] = f2bf(v2) | (f2bf(v3) << 16);
                *(u32x2*)((char*)z_sh + k * ZROWB + px0 * 2) = wpk;
            }
        }
    }

    __syncthreads();

    // ---- involution: thread = (c2, y8, xh); 2-deep pipelined kh ----
    const int c2 = tid >> 4;
    const int y8 = (tid >> 1) & 7;
    const int xh = tid & 1;
    const bool ledge = (bx == 0) & (xh == 0);
    const bool redge = (bx == W_ / TW - 1) & (xh == 1);

    float a0 = 0.f, a1 = 0.f, a2 = 0.f, a3 = 0.f;
    float a4 = 0.f, a5 = 0.f, a6 = 0.f, a7 = 0.f;

    const float* xc = x + (size_t)(b * C_ + g * GC_ + c2) * HW_;
    const char* zby = (const char*)z_sh + y8 * 32 + xh * 16;

    auto loadrow = [&](float* R, int KH) {
        const int gh  = h0 + y8 + KH - PAD;
        const int ghc = gh < 0 ? 0 : (gh > H_ - 1 ? H_ - 1 : gh);
        const float* rp = xc + (size_t)ghc * W_;
        if (ledge) {
            const f32x4* vp = (const f32x4*)rp;               // x = 0..11
            const f32x4 q0 = vp[0], q1 = vp[1], q2 = vp[2];
            R[0] = 0.f; R[1] = 0.f; R[2] = 0.f;
            R[3] = q0[0]; R[4] = q0[1]; R[5] = q0[2]; R[6] = q0[3];
            R[7] = q1[0]; R[8] = q1[1]; R[9] = q1[2]; R[10] = q1[3];
            R[11] = q2[0]; R[12] = q2[1]; R[13] = q2[2];
        } else if (redge) {
            const f32x4* vp = (const f32x4*)(rp + 116);       // x = 116..127
            const f32x4 q0 = vp[0], q1 = vp[1], q2 = vp[2];
            R[0] = q0[1]; R[1] = q0[2]; R[2] = q0[3];
            R[3] = q1[0]; R[4] = q1[1]; R[5] = q1[2]; R[6] = q1[3];
            R[7] = q2[0]; R[8] = q2[1]; R[9] = q2[2]; R[10] = q2[3];
            R[11] = 0.f; R[12] = 0.f; R[13] = 0.f;
        } else {
            const f32x4* vp = (const f32x4*)(rp + w0 + xh * 8 - 4);
            const f32x4 q0 = vp[0], q1 = vp[1], q2 = vp[2], q3 = vp[3];
            R[0] = q0[1]; R[1] = q0[2]; R[2] = q0[3];
            R[3] = q1[0]; R[4] = q1[1]; R[5] = q1[2]; R[6] = q1[3];
            R[7] = q2[0]; R[8] = q2[1]; R[9] = q2[2]; R[10] = q2[3];
            R[11] = q3[0]; R[12] = q3[1]; R[13] = q3[2];
        }
    };

    auto fmablk = [&](const float* R, int KH) {
        const int gh = h0 + y8 + KH - PAD;
        if (gh >= 0 && gh < H_) {
            const char* zrow = zby + KH * (KS * ZROWB);
#pragma unroll
            for (int kw = 0; kw < KS; ++kw) {
                const u32x4 q = *(const u32x4*)(zrow + kw * ZROWB);  // 8 px
                a0 = fmaf(BFLO(q[0]), R[kw + 0], a0);
                a1 = fmaf(BFHI(q[0]), R[kw + 1], a1);
                a2 = fmaf(BFLO(q[1]), R[kw + 2], a2);
                a3 = fmaf(BFHI(q[1]), R[kw + 3], a3);
                a4 = fmaf(BFLO(q[2]), R[kw + 4], a4);
                a5 = fmaf(BFHI(q[2]), R[kw + 5], a5);
                a6 = fmaf(BFLO(q[3]), R[kw + 6], a6);
                a7 = fmaf(BFHI(q[3]), R[kw + 7], a7);
            }
        }
    };

    float rowA[14], rowB[14];
    loadrow(rowA, 0);
#pragma unroll 1
    for (int kh2 = 0; kh2 < 3; ++kh2) {
        loadrow(rowB, 2 * kh2 + 1);   // issue next-row loads
        fmablk(rowA, 2 * kh2);        // compute current (hides rowB latency)
        loadrow(rowA, 2 * kh2 + 2);
        fmablk(rowB, 2 * kh2 + 1);
    }
    fmablk(rowA, 6);

    // ---- coalesced stores: 2x float4 ----
    float* og = out + (size_t)(b * C_ + g * GC_ + c2) * HW_
                    + (h0 + y8) * W_ + w0 + xh * 8;
    {
        f32x4 v;
        v[0] = a0; v[1] = a1; v[2] = a2; v[3] = a3;
        *(f32x4*)(og + 0) = v;
        v[0] = a4; v[1] = a5; v[2] = a6; v[3] = a7;
        *(f32x4*)(og + 4) = v;
    }
}

extern "C" void kernel_launch(void* const* d_in, const int* in_sizes, int n_in,
                              void* d_out, int out_size, void* d_ws, size_t ws_size,
                              hipStream_t stream) {
    const float* x   = (const float*)d_in[0];
    const float* cw  = (const float*)d_in[1];
    const float* bng = (const float*)d_in[2];
    const float* bnb = (const float*)d_in[3];
    const float* bnm = (const float*)d_in[4];
    const float* bnv = (const float*)d_in[5];
    float* out = (float*)d_out;

    dim3 grid(2048);   // 1D so the XCD swizzle controls bid&7 directly
    dim3 block(256);
    invol_mfma9<<<grid, block, 0, stream>>>(x, cw, bng, bnb, bnm, bnv, out);
}

// Round 14
// 50.467 us; speedup vs baseline: 1.5401x; 1.0148x over previous
//
#include <hip/hip_runtime.h>

#define B_   4
#define C_   64
#define H_   128
#define W_   128
#define KS   7
#define G_   4
#define GC_  16
#define KK   49
#define PAD  3
#define TH   8
#define TW   16
#define HW_  (H_ * W_)
#define ZROWB 288              // LDS z row stride (bytes): 128 px * 2B + 32B pad

typedef float f32x4  __attribute__((ext_vector_type(4)));
typedef short bf16x8 __attribute__((ext_vector_type(8)));
typedef unsigned int u32x4 __attribute__((ext_vector_type(4)));
typedef unsigned int u32x2 __attribute__((ext_vector_type(2)));

__device__ __forceinline__ unsigned f2bf(float f) {   // RNE float->bf16 (low 16)
    unsigned u = __float_as_uint(f);
    unsigned r = u + 0x7FFFu + ((u >> 16) & 1u);
    return r >> 16;
}

#define BFLO(u) __uint_as_float((u) << 16)
#define BFHI(u) __uint_as_float((u) & 0xFFFF0000u)

// ======== prep: xT[b][hw][c] bf16  +  BN-folded bf16 weights (64 k-rows) ====
__global__ __launch_bounds__(256) void prep(
    const float* __restrict__ x,
    const float* __restrict__ cw,
    const float* __restrict__ bng,
    const float* __restrict__ bnv,
    unsigned short* __restrict__ xT,
    unsigned short* __restrict__ cwb)
{
    const int tid = threadIdx.x;
    const int bid = blockIdx.x;
    if (bid < 1024) {
        // transpose 64 px x 64 c tile of image b
        __shared__ unsigned short t[64][68];
        const int b   = bid >> 8;
        const int px0 = (bid & 255) * 64;
        const float* xb = x + (size_t)b * C_ * HW_ + px0;
#pragma unroll
        for (int it = 0; it < 16; ++it) {
            const int i = it * 256 + tid;
            const int c = i >> 6, p = i & 63;
            t[p][c] = (unsigned short)f2bf(xb[(size_t)c * HW_ + p]);
        }
        __syncthreads();
        const int p = tid >> 2, q = tid & 3;
        unsigned int o[8];
#pragma unroll
        for (int j = 0; j < 8; ++j)
            o[j] = (unsigned)t[p][q * 16 + 2 * j] | ((unsigned)t[p][q * 16 + 2 * j + 1] << 16);
        unsigned int* dst = (unsigned int*)(xT + ((size_t)(b * HW_ + px0 + p)) * C_ + q * 16);
        u32x4 v0, v1;
        v0[0] = o[0]; v0[1] = o[1]; v0[2] = o[2]; v0[3] = o[3];
        v1[0] = o[4]; v1[1] = o[5]; v1[2] = o[6]; v1[3] = o[7];
        *(u32x4*)dst = v0;
        *(u32x4*)(dst + 4) = v1;
    } else {
        // weights: thread -> (g, kp); rows kp>=49 are zero (k-pad, kills guard)
        const int g  = tid >> 6;
        const int kp = tid & 63;
        unsigned int* dst = (unsigned int*)(cwb + ((size_t)(g * 64 + kp)) * C_);
        if (kp < KK) {
            const int o = g * KK + kp;
            const float sc = bng[o] * rsqrtf(bnv[o] + 1e-5f);
            const float* wp = cw + (size_t)o * C_;
#pragma unroll
            for (int c = 0; c < C_; c += 2)
                dst[c >> 1] = f2bf(wp[c] * sc) | (f2bf(wp[c + 1] * sc) << 16);
        } else {
#pragma unroll
            for (int c2 = 0; c2 < C_ / 2; ++c2) dst[c2] = 0u;
        }
    }
}

// ======== main: fused conv(MFMA, precomputed frags) + involution ========
__global__ __launch_bounds__(256, 4) void invol_mfma10(
    const float* __restrict__ x,
    const unsigned short* __restrict__ xT,
    const unsigned short* __restrict__ cwb,
    const float* __restrict__ bng,
    const float* __restrict__ bnb,
    const float* __restrict__ bnm,
    const float* __restrict__ bnv,
    float* __restrict__ out)
{
    __shared__ __align__(16) unsigned short z_sh[KK * (ZROWB / 2)]; // 14112 B
    __shared__ float sbias[KK];

    const int tid  = threadIdx.x;
    const int lane = tid & 63;
    const int wv   = tid >> 6;
    const int l15  = lane & 15;
    const int l4   = lane >> 4;

    // XCD-locality swizzle (r13: FETCH 37->27 MB confirmed): bid&7 = XCD,
    // each XCD owns one (b, g-pair) = 4 MB x footprint = its L2.
    const int bid = blockIdx.x;
    const int xcd = bid & 7;
    const int s   = bid >> 3;
    const int b   = xcd >> 1;
    const int g   = (xcd & 1) * 2 + (s >> 7);
    const int by  = (s >> 3) & 15;
    const int bx  = s & 7;
    const int w0  = bx * TW;
    const int h0  = by * TH;

    if (tid < KK) {
        const int o = g * KK + tid;
        const float sc = bng[o] * rsqrtf(bnv[o] + 1e-5f);
        sbias[tid] = bnb[o] - bnm[o] * sc;      // scale folded into cwb
    }

    // ---- A fragments: one dwordx4 each (xT is [hw][c] bf16) ----
    bf16x8 afr[2][2];
    {
        const unsigned short* xTb = xT + (size_t)b * HW_ * C_;
#pragma unroll
        for (int mt = 0; mt < 2; ++mt) {
            const int hh = h0 + wv * 2 + mt;
            const unsigned short* xp = xTb + ((size_t)(hh * W_ + w0 + l15)) * C_;
#pragma unroll
            for (int ks = 0; ks < 2; ++ks)
                afr[mt][ks] = *(const bf16x8*)(xp + ks * 32 + l4 * 8);
        }
    }

    // ---- B fragments: one dwordx4 each (cwb is [g][64k][c] bf16, folded) ----
    bf16x8 bfr[4][2];
    {
        const unsigned short* cwg = cwb + (size_t)g * 64 * C_;
#pragma unroll
        for (int nt = 0; nt < 4; ++nt) {
            const int k = nt * 16 + l15;
#pragma unroll
            for (int ks = 0; ks < 2; ++ks)
                bfr[nt][ks] = *(const bf16x8*)(cwg + k * C_ + ks * 32 + l4 * 8);
        }
    }

    __syncthreads();   // sbias visible

    // ---- MFMA: z[px][k] ----
    f32x4 acc1[2][4];
#pragma unroll
    for (int mt = 0; mt < 2; ++mt)
#pragma unroll
        for (int nt = 0; nt < 4; ++nt) {
            f32x4 a = {0.f, 0.f, 0.f, 0.f};
            a = __builtin_amdgcn_mfma_f32_16x16x32_bf16(afr[mt][0], bfr[nt][0], a, 0, 0, 0);
            a = __builtin_amdgcn_mfma_f32_16x16x32_bf16(afr[mt][1], bfr[nt][1], a, 0, 0, 0);
            acc1[mt][nt] = a;
        }

    // ---- epilogue: +bias, SiLU, pack -> z_sh[k][px] ----
#pragma unroll
    for (int nt = 0; nt < 4; ++nt) {
        const int k = nt * 16 + l15;
        if (k < KK) {
            const float bi = sbias[k];
#pragma unroll
            for (int mt = 0; mt < 2; ++mt) {
                const int px0 = (wv * 2 + mt) * 16 + l4 * 4;
                const float t0 = acc1[mt][nt][0] + bi;
                const float t1 = acc1[mt][nt][1] + bi;
                const float t2 = acc1[mt][nt][2] + bi;
                const float t3 = acc1[mt][nt][3] + bi;
                const float v0 = __fdividef(t0, 1.0f + __expf(-t0));
                const float v1 = __fdividef(t1, 1.0f + __expf(-t1));
                const float v2 = __fdividef(t2, 1.0f + __expf(-t2));
                const float v3 = __fdividef(t3, 1.0f + __expf(-t3));
                u32x2 wpk;
                wpk[0] = f2bf(v0) | (f2bf(v1) << 16);
                wpk[1] = f2bf(v2) | (f2bf(v3) << 16);
                *(u32x2*)((char*)z_sh + k * ZROWB + px0 * 2) = wpk;
            }
        }
    }

    __syncthreads();   // z visible

    // ---- involution: thread = (c2, y8, xh); 2-deep pipelined kh ----
    const int c2 = tid >> 4;
    const int y8 = (tid >> 1) & 7;
    const int xh = tid & 1;
    const bool ledge = (bx == 0) & (xh == 0);
    const bool redge = (bx == W_ / TW - 1) & (xh == 1);

    float a0 = 0.f, a1 = 0.f, a2 = 0.f, a3 = 0.f;
    float a4 = 0.f, a5 = 0.f, a6 = 0.f, a7 = 0.f;

    const float* xc = x + (size_t)(b * C_ + g * GC_ + c2) * HW_;
    const char* zby = (const char*)z_sh + y8 * 32 + xh * 16;

    auto loadrow = [&](float* R, int KH) {
        const int gh  = h0 + y8 + KH - PAD;
        const int ghc = gh < 0 ? 0 : (gh > H_ - 1 ? H_ - 1 : gh);
        const float* rp = xc + (size_t)ghc * W_;
        if (ledge) {
            const f32x4* vp = (const f32x4*)rp;               // x = 0..11
            const f32x4 q0 = vp[0], q1 = vp[1], q2 = vp[2];
            R[0] = 0.f; R[1] = 0.f; R[2] = 0.f;
            R[3] = q0[0]; R[4] = q0[1]; R[5] = q0[2]; R[6] = q0[3];
            R[7] = q1[0]; R[8] = q1[1]; R[9] = q1[2]; R[10] = q1[3];
            R[11] = q2[0]; R[12] = q2[1]; R[13] = q2[2];
        } else if (redge) {
            const f32x4* vp = (const f32x4*)(rp + 116);       // x = 116..127
            const f32x4 q0 = vp[0], q1 = vp[1], q2 = vp[2];
            R[0] = q0[1]; R[1] = q0[2]; R[2] = q0[3];
            R[3] = q1[0]; R[4] = q1[1]; R[5] = q1[2]; R[6] = q1[3];
            R[7] = q2[0]; R[8] = q2[1]; R[9] = q2[2]; R[10] = q2[3];
            R[11] = 0.f; R[12] = 0.f; R[13] = 0.f;
        } else {
            const f32x4* vp = (const f32x4*)(rp + w0 + xh * 8 - 4);
            const f32x4 q0 = vp[0], q1 = vp[1], q2 = vp[2], q3 = vp[3];
            R[0] = q0[1]; R[1] = q0[2]; R[2] = q0[3];
            R[3] = q1[0]; R[4] = q1[1]; R[5] = q1[2]; R[6] = q1[3];
            R[7] = q2[0]; R[8] = q2[1]; R[9] = q2[2]; R[10] = q2[3];
            R[11] = q3[0]; R[12] = q3[1]; R[13] = q3[2];
        }
    };

    auto fmablk = [&](const float* R, int KH) {
        const int gh = h0 + y8 + KH - PAD;
        if (gh >= 0 && gh < H_) {
            const char* zrow = zby + KH * (KS * ZROWB);
#pragma unroll
            for (int kw = 0; kw < KS; ++kw) {
                const u32x4 q = *(const u32x4*)(zrow + kw * ZROWB);  // 8 px
                a0 = fmaf(BFLO(q[0]), R[kw + 0], a0);
                a1 = fmaf(BFHI(q[0]), R[kw + 1], a1);
                a2 = fmaf(BFLO(q[1]), R[kw + 2], a2);
                a3 = fmaf(BFHI(q[1]), R[kw + 3], a3);
                a4 = fmaf(BFLO(q[2]), R[kw + 4], a4);
                a5 = fmaf(BFHI(q[2]), R[kw + 5], a5);
                a6 = fmaf(BFLO(q[3]), R[kw + 6], a6);
                a7 = fmaf(BFHI(q[3]), R[kw + 7], a7);
            }
        }
    };

    float rowA[14], rowB[14];
    loadrow(rowA, 0);
#pragma unroll 1
    for (int kh2 = 0; kh2 < 3; ++kh2) {
        loadrow(rowB, 2 * kh2 + 1);
        fmablk(rowA, 2 * kh2);
        loadrow(rowA, 2 * kh2 + 2);
        fmablk(rowB, 2 * kh2 + 1);
    }
    fmablk(rowA, 6);

    float* og = out + (size_t)(b * C_ + g * GC_ + c2) * HW_
                    + (h0 + y8) * W_ + w0 + xh * 8;
    {
        f32x4 v;
        v[0] = a0; v[1] = a1; v[2] = a2; v[3] = a3;
        *(f32x4*)(og + 0) = v;
        v[0] = a4; v[1] = a5; v[2] = a6; v[3] = a7;
        *(f32x4*)(og + 4) = v;
    }
}

extern "C" void kernel_launch(void* const* d_in, const int* in_sizes, int n_in,
                              void* d_out, int out_size, void* d_ws, size_t ws_size,
                              hipStream_t stream) {
    const float* x   = (const float*)d_in[0];
    const float* cw  = (const float*)d_in[1];
    const float* bng = (const float*)d_in[2];
    const float* bnb = (const float*)d_in[3];
    const float* bnm = (const float*)d_in[4];
    const float* bnv = (const float*)d_in[5];
    float* out = (float*)d_out;

    unsigned short* xT  = (unsigned short*)d_ws;                 // 8,388,608 B
    unsigned short* cwb = xT + (size_t)B_ * HW_ * C_;            // 32,768 B

    prep<<<dim3(1025), dim3(256), 0, stream>>>(x, cw, bng, bnv, xT, cwb);
    invol_mfma10<<<dim3(2048), dim3(256), 0, stream>>>(x, xT, cwb,
                                                       bng, bnb, bnm, bnv, out);
}